// Round 1
// baseline (1008.657 us; speedup 1.0000x reference)
//
#include <hip/hip_runtime.h>
#include <math.h>

#define E_N   8192
#define HID   128
#define NRAD  64
#define KNB   32
#define CUTF  10.0f
#define LNEPS 1e-5f

__device__ __forceinline__ unsigned long long shflx64(unsigned long long v, int m) {
  int lo = __shfl_xor((int)(v & 0xffffffffull), m, 64);
  int hi = __shfl_xor((int)(v >> 32), m, 64);
  return ((unsigned long long)(unsigned)hi << 32) | (unsigned)lo;
}

// monotone map of f32 to u32 (handles negatives), packed with index for
// "min d2, tie -> min index" selection matching jax.lax.top_k stability.
__device__ __forceinline__ unsigned long long d2key(float v, int j) {
  unsigned u = __float_as_uint(v);
  u = (u & 0x80000000u) ? ~u : (u | 0x80000000u);
  return ((unsigned long long)u << 32) | (unsigned)j;
}

// ---------------- kernel 1: edge centers + squared norms ----------------
__global__ void k_prep(const float* __restrict__ nc, const int* __restrict__ ei,
                       float* __restrict__ cen, float* __restrict__ n2) {
  int e = blockIdx.x * 256 + threadIdx.x;
  if (e >= E_N) return;
  int a = ei[e], b = ei[E_N + e];
  float x = (nc[a*3+0] + nc[b*3+0]) * 0.5f;
  float y = (nc[a*3+1] + nc[b*3+1]) * 0.5f;
  float z = (nc[a*3+2] + nc[b*3+2]) * 0.5f;
  cen[e*3+0] = x; cen[e*3+1] = y; cen[e*3+2] = z;
  n2[e] = x*x + y*y + z*z;
}

// ---------------- kernel 2: top-K nearest edge centers ----------------
// one 256-thread block per row; each thread holds 32 candidates in regs;
// 32 extract-min iterations with owner-only rescan.
__global__ __launch_bounds__(256) void k_topk(const float* __restrict__ cen,
    const float* __restrict__ n2, int* __restrict__ idxo) {
  const int row = blockIdx.x;
  const int t = threadIdx.x;
  const float cx = cen[row*3+0], cy = cen[row*3+1], cz = cen[row*3+2];
  const float n2i = n2[row];
  float vals[32];
  #pragma unroll
  for (int s = 0; s < 32; ++s) {
    int j = t + (s << 8);
    float dot = cx*cen[j*3+0] + cy*cen[j*3+1] + cz*cen[j*3+2];
    vals[s] = (n2i + n2[j]) - 2.0f*dot;   // gram trick, same as reference
  }
  unsigned long long lk = d2key(vals[0], t);
  #pragma unroll
  for (int s = 1; s < 32; ++s) {
    unsigned long long kk = d2key(vals[s], t + (s << 8));
    lk = kk < lk ? kk : lk;
  }
  __shared__ unsigned long long wmin[4];
  __shared__ unsigned long long winner;
  for (int kk = 0; kk < KNB; ++kk) {
    unsigned long long r = lk;
    #pragma unroll
    for (int m = 1; m < 64; m <<= 1) {
      unsigned long long o = shflx64(r, m);
      r = o < r ? o : r;
    }
    if ((t & 63) == 0) wmin[t >> 6] = r;
    __syncthreads();
    if (t == 0) {
      unsigned long long w0 = wmin[0];
      if (wmin[1] < w0) w0 = wmin[1];
      if (wmin[2] < w0) w0 = wmin[2];
      if (wmin[3] < w0) w0 = wmin[3];
      winner = w0;
      idxo[row*KNB + kk] = (int)(w0 & 0xffffffffu);
    }
    __syncthreads();
    int jw = (int)(winner & 0xffffffffu);
    if ((jw & 255) == t) {            // owner removes and rescans
      int sw = jw >> 8;
      #pragma unroll
      for (int s = 0; s < 32; ++s) if (s == sw) vals[s] = __uint_as_float(0x7f800000u);
      lk = d2key(vals[0], t);
      #pragma unroll
      for (int s = 1; s < 32; ++s) {
        unsigned long long kk2 = d2key(vals[s], t + (s << 8));
        lk = kk2 < lk ? kk2 : lk;
      }
    }
  }
}

// ---------------- kernel 3: q,k,v projections + coordinate gates ----------------
__global__ void k_qkv_gates(const float* __restrict__ ef,
    const float* __restrict__ Wq, const float* __restrict__ Wk, const float* __restrict__ Wv,
    const float* __restrict__ Wg1, const float* __restrict__ bg1,
    const float* __restrict__ Wg2, const float* __restrict__ bg2,
    float* __restrict__ qf, float* __restrict__ kf, float* __restrict__ vf,
    float* __restrict__ gates) {
  int e = blockIdx.x, o = threadIdx.x;   // 128 threads
  __shared__ float efs[HID];
  __shared__ float vs[HID];
  __shared__ float red[2];
  efs[o] = ef[e*HID + o];
  __syncthreads();
  float aq = 0.f, ak = 0.f, av = 0.f;
  #pragma unroll 8
  for (int d = 0; d < HID; ++d) {
    float a = efs[d];
    aq = fmaf(a, Wq[d*HID + o], aq);
    ak = fmaf(a, Wk[d*HID + o], ak);
    av = fmaf(a, Wv[d*HID + o], av);
  }
  qf[e*HID + o] = aq; kf[e*HID + o] = ak; vf[e*HID + o] = av;
  vs[o] = av;
  __syncthreads();
  float g = 0.f;
  #pragma unroll 8
  for (int d = 0; d < HID; ++d) g = fmaf(vs[d], Wg1[d*HID + o], g);
  g += bg1[o];
  g = g / (1.0f + expf(-g));            // silu
  float part = g * Wg2[o];
  #pragma unroll
  for (int m = 1; m < 64; m <<= 1) part += __shfl_xor(part, m, 64);
  if ((o & 63) == 0) red[o >> 6] = part;
  __syncthreads();
  if (o == 0) {
    float s = red[0] + red[1] + bg2[0];
    gates[e] = 1.0f / (1.0f + expf(-s));
  }
}

// ---------------- kernel 4: per-pair geometry + q.k dot ----------------
__global__ void k_geom(const float* __restrict__ cen, const int* __restrict__ idx,
    const float* __restrict__ qf, const float* __restrict__ kf,
    float* __restrict__ dist, float* __restrict__ cdiff, float* __restrict__ dotv) {
  int p = blockIdx.x * 4 + (threadIdx.x >> 6);
  int lane = threadIdx.x & 63;
  int e = p >> 5;
  int j = idx[p];
  float s = qf[e*HID + lane] * kf[j*HID + lane]
          + qf[e*HID + 64 + lane] * kf[j*HID + 64 + lane];
  #pragma unroll
  for (int m = 1; m < 64; m <<= 1) s += __shfl_xor(s, m, 64);
  if (lane == 0) {
    dotv[p] = s;
    float dx = cen[e*3+0] - cen[j*3+0];
    float dy = cen[e*3+1] - cen[j*3+1];
    float dz = cen[e*3+2] - cen[j*3+2];
    dist[p] = sqrtf(dx*dx + dy*dy + dz*dz);
    cdiff[p*3+0] = dx; cdiff[p*3+1] = dy; cdiff[p*3+2] = dz;
  }
}

// ---------------- kernel 5: fused attention MLP -> scores ----------------
// BM=64 rows (2 edges x 32 nbrs), BN=128, BK=64; 256 threads, 4x8 acc each.
__global__ __launch_bounds__(256) void k_mlp(
    const float* __restrict__ qf, const float* __restrict__ kf,
    const int* __restrict__ idx, const float* __restrict__ dist,
    const float* __restrict__ dotv,
    const float* __restrict__ W1, const float* __restrict__ b1,
    const float* __restrict__ W2, const float* __restrict__ b2,
    const float* __restrict__ W3, const float* __restrict__ b3,
    const float* __restrict__ centers, const float* __restrict__ widths,
    float* __restrict__ scores) {
  __shared__ __align__(16) float pool[16384];           // 64 KiB
  float (*sA)[68]  = (float(*)[68])pool;                // [dd][row] transposed A chunk
  float (*sH)[128] = (float(*)[128])pool;               // [row][o] h1 (aliases sA)
  float (*sW)[128] = (float(*)[128])(pool + 8192);      // [dd][o] weight chunk

  const int t  = threadIdx.x;
  const int tx = t & 15, ty = t >> 4;
  const int rowbase = blockIdx.x * 64;

  // staging mapping: thread covers row (t>>2), dd quarter (t&3)
  const int sb = t & 3;
  const int srow = t >> 2;
  const int sp = rowbase + srow;
  const int se = sp >> 5;
  const int sj = idx[sp];
  const float sdist = dist[sp];
  const float sincut = (sdist <= CUTF) ? 1.0f : 0.0f;

  float acc[4][8];
  #pragma unroll
  for (int rr = 0; rr < 4; ++rr)
    #pragma unroll
    for (int cc = 0; cc < 8; ++cc) acc[rr][cc] = 0.0f;

  // -------- GEMM1: d-chunks 0..319 (q | k_j | rbf) --------
  for (int c = 0; c < 5; ++c) {
    const int dbase = c * 64;
    if (c < 4) {
      const float* src = (c < 2) ? (qf + se*HID + dbase) : (kf + sj*HID + (dbase - 128));
      #pragma unroll
      for (int i4 = 0; i4 < 4; ++i4) {
        float4 vv = *(const float4*)(src + sb*16 + i4*4);
        sA[sb*16 + i4*4 + 0][srow] = vv.x;
        sA[sb*16 + i4*4 + 1][srow] = vv.y;
        sA[sb*16 + i4*4 + 2][srow] = vv.z;
        sA[sb*16 + i4*4 + 3][srow] = vv.w;
      }
    } else {
      #pragma unroll
      for (int ii = 0; ii < 16; ++ii) {
        int nr = sb*16 + ii;
        float df = sdist - centers[nr];
        sA[nr][srow] = expf(-widths[nr]*df*df) * sincut;
      }
    }
    #pragma unroll
    for (int m = 0; m < 32; ++m) {
      int ii = t + (m << 8);
      sW[ii >> 7][ii & 127] = W1[(dbase + (ii >> 7))*HID + (ii & 127)];
    }
    __syncthreads();
    #pragma unroll 4
    for (int dd = 0; dd < 64; ++dd) {
      float4 a4 = *(const float4*)&sA[dd][ty*4];
      float4 b0 = *(const float4*)&sW[dd][tx*8];
      float4 b4 = *(const float4*)&sW[dd][tx*8 + 4];
      float av[4] = {a4.x, a4.y, a4.z, a4.w};
      float bv[8] = {b0.x, b0.y, b0.z, b0.w, b4.x, b4.y, b4.z, b4.w};
      #pragma unroll
      for (int rr = 0; rr < 4; ++rr)
        #pragma unroll
        for (int cc = 0; cc < 8; ++cc)
          acc[rr][cc] = fmaf(av[rr], bv[cc], acc[rr][cc]);
    }
    __syncthreads();
  }

  // -------- dot term (d=320) + bias + silu -> sH --------
  {
    float w320[8], b1r[8];
    #pragma unroll
    for (int cc = 0; cc < 8; ++cc) {
      w320[cc] = W1[320*HID + tx*8 + cc];
      b1r[cc]  = b1[tx*8 + cc];
    }
    #pragma unroll
    for (int rr = 0; rr < 4; ++rr) {
      float dv = dotv[rowbase + ty*4 + rr];
      #pragma unroll
      for (int cc = 0; cc < 8; ++cc) {
        float x = acc[rr][cc] + dv*w320[cc] + b1r[cc];
        sH[ty*4 + rr][tx*8 + cc] = x / (1.0f + expf(-x));
        acc[rr][cc] = 0.0f;
      }
    }
  }
  __syncthreads();

  // -------- GEMM2: h1 @ W2 --------
  for (int ch = 0; ch < 2; ++ch) {
    #pragma unroll
    for (int m = 0; m < 32; ++m) {
      int ii = t + (m << 8);
      sW[ii >> 7][ii & 127] = W2[(ch*64 + (ii >> 7))*HID + (ii & 127)];
    }
    __syncthreads();
    #pragma unroll 4
    for (int dd = 0; dd < 64; ++dd) {
      int d = ch*64 + dd;
      float av[4];
      #pragma unroll
      for (int rr = 0; rr < 4; ++rr) av[rr] = sH[ty*4 + rr][d];
      float4 b0 = *(const float4*)&sW[dd][tx*8];
      float4 b4 = *(const float4*)&sW[dd][tx*8 + 4];
      float bv[8] = {b0.x, b0.y, b0.z, b0.w, b4.x, b4.y, b4.z, b4.w};
      #pragma unroll
      for (int rr = 0; rr < 4; ++rr)
        #pragma unroll
        for (int cc = 0; cc < 8; ++cc)
          acc[rr][cc] = fmaf(av[rr], bv[cc], acc[rr][cc]);
    }
    __syncthreads();
  }

  // -------- epilogue: silu, raw = h2 @ W3 + b3, cutoff mask --------
  {
    float b2r[8], w3r[8];
    #pragma unroll
    for (int cc = 0; cc < 8; ++cc) { b2r[cc] = b2[tx*8 + cc]; w3r[cc] = W3[tx*8 + cc]; }
    float bb3 = b3[0];
    #pragma unroll
    for (int rr = 0; rr < 4; ++rr) {
      float part = 0.0f;
      #pragma unroll
      for (int cc = 0; cc < 8; ++cc) {
        float x = acc[rr][cc] + b2r[cc];
        float h = x / (1.0f + expf(-x));
        part = fmaf(h, w3r[cc], part);
      }
      #pragma unroll
      for (int m = 1; m < 16; m <<= 1) part += __shfl_xor(part, m, 64);
      if (tx == 0) {
        int p = rowbase + ty*4 + rr;
        float raw = part + bb3;
        scores[p] = (dist[p] <= CUTF) ? raw : 0.0f;
      }
    }
  }
}

// ---------------- kernel 6: softmax + weighted V + coord update ----------------
__global__ void k_combine(const float* __restrict__ scores, const int* __restrict__ idx,
    const float* __restrict__ vf, const float* __restrict__ gates,
    const float* __restrict__ cdiff, const float* __restrict__ ef,
    const float* __restrict__ ec, float* __restrict__ upd, float* __restrict__ outc) {
  int e = blockIdx.x, t = threadIdx.x;   // 128 threads
  __shared__ float wk[KNB], wg[KNB];
  __shared__ int jj[KNB];
  if (t < 64) {
    float sc = (t < KNB) ? scores[e*KNB + t] : -1e30f;
    float m = sc;
    #pragma unroll
    for (int mm = 1; mm < 32; mm <<= 1) m = fmaxf(m, __shfl_xor(m, mm, 64));
    m = fmaxf(m, 0.0f);
    float ex = (t < KNB) ? expf(sc - m) : 0.0f;
    float Z = ex;
    #pragma unroll
    for (int mm = 1; mm < 32; mm <<= 1) Z += __shfl_xor(Z, mm, 64);
    Z += 8160.0f * expf(-m);             // (E-K) zero-score tail
    if (t < KNB) {
      float w = ex / Z;
      int j = idx[e*KNB + t];
      jj[t] = j; wk[t] = w; wg[t] = w * gates[j];
    }
  }
  __syncthreads();
  float acc = 0.0f;
  #pragma unroll 4
  for (int kk = 0; kk < KNB; ++kk) acc = fmaf(wk[kk], vf[jj[kk]*HID + t], acc);
  upd[e*HID + t] = ef[e*HID + t] + acc;
  if (t < 3) {
    float csum = 0.0f;
    #pragma unroll 4
    for (int kk = 0; kk < KNB; ++kk) csum = fmaf(wg[kk], cdiff[(e*KNB + kk)*3 + t], csum);
    outc[e*3 + t] = ec[e*3 + t] + csum;
  }
}

// ---------------- kernel 7: output projection + residual + LayerNorm ----------------
__global__ void k_out(const float* __restrict__ upd, const float* __restrict__ ef,
    const float* __restrict__ Wo, const float* __restrict__ bo,
    const float* __restrict__ gamma, const float* __restrict__ beta,
    float* __restrict__ outf) {
  int e = blockIdx.x, o = threadIdx.x;   // 128 threads
  __shared__ float us[HID];
  __shared__ float red2[2];
  us[o] = upd[e*HID + o];
  __syncthreads();
  float a = 0.0f;
  #pragma unroll 8
  for (int d = 0; d < HID; ++d) a = fmaf(us[d], Wo[d*HID + o], a);
  float x = ef[e*HID + o] + a + bo[o];
  float s = x;
  #pragma unroll
  for (int m = 1; m < 64; m <<= 1) s += __shfl_xor(s, m, 64);
  if ((o & 63) == 0) red2[o >> 6] = s;
  __syncthreads();
  float mu = (red2[0] + red2[1]) * (1.0f/128.0f);
  __syncthreads();
  float dv = x - mu;
  float s2 = dv*dv;
  #pragma unroll
  for (int m = 1; m < 64; m <<= 1) s2 += __shfl_xor(s2, m, 64);
  if ((o & 63) == 0) red2[o >> 6] = s2;
  __syncthreads();
  float var = (red2[0] + red2[1]) * (1.0f/128.0f);
  outf[e*HID + o] = dv * rsqrtf(var + LNEPS) * gamma[o] + beta[o];
}

extern "C" void kernel_launch(void* const* d_in, const int* in_sizes, int n_in,
                              void* d_out, int out_size, void* d_ws, size_t ws_size,
                              hipStream_t stream) {
  const float* ef   = (const float*)d_in[0];
  const float* ec   = (const float*)d_in[1];
  const float* nc   = (const float*)d_in[2];
  const float* Wq   = (const float*)d_in[3];
  const float* Wk   = (const float*)d_in[4];
  const float* Wv   = (const float*)d_in[5];
  const float* W1   = (const float*)d_in[6];
  const float* b1   = (const float*)d_in[7];
  const float* W2   = (const float*)d_in[8];
  const float* b2   = (const float*)d_in[9];
  const float* W3   = (const float*)d_in[10];
  const float* b3   = (const float*)d_in[11];
  const float* Wg1  = (const float*)d_in[12];
  const float* bg1  = (const float*)d_in[13];
  const float* Wg2  = (const float*)d_in[14];
  const float* bg2  = (const float*)d_in[15];
  const float* Wo   = (const float*)d_in[16];
  const float* bo   = (const float*)d_in[17];
  const float* gamma= (const float*)d_in[18];
  const float* beta = (const float*)d_in[19];
  const float* centers = (const float*)d_in[20];
  const float* widths  = (const float*)d_in[21];
  const int*   eidx    = (const int*)d_in[22];

  float* outf = (float*)d_out;
  float* outc = outf + (size_t)E_N * HID;

  float* cen   = (float*)d_ws;
  float* n2    = cen + 3*E_N;
  int*   idx   = (int*)(n2 + E_N);
  float* dist  = (float*)(idx + E_N*KNB);
  float* cdiff = dist + E_N*KNB;
  float* dotv  = cdiff + 3*E_N*KNB;
  float* qf    = dotv + E_N*KNB;
  float* kf    = qf + (size_t)E_N*HID;
  float* vf    = kf + (size_t)E_N*HID;
  float* scores= vf + (size_t)E_N*HID;
  float* gates = scores + E_N*KNB;
  float* upd   = gates + E_N;

  k_prep<<<E_N/256, 256, 0, stream>>>(nc, eidx, cen, n2);
  k_topk<<<E_N, 256, 0, stream>>>(cen, n2, idx);
  k_qkv_gates<<<E_N, 128, 0, stream>>>(ef, Wq, Wk, Wv, Wg1, bg1, Wg2, bg2, qf, kf, vf, gates);
  k_geom<<<E_N*KNB/4, 256, 0, stream>>>(cen, idx, qf, kf, dist, cdiff, dotv);
  k_mlp<<<E_N*KNB/64, 256, 0, stream>>>(qf, kf, idx, dist, dotv, W1, b1, W2, b2, W3, b3,
                                        centers, widths, scores);
  k_combine<<<E_N, 128, 0, stream>>>(scores, idx, vf, gates, cdiff, ef, ec, upd, outc);
  k_out<<<E_N, 128, 0, stream>>>(upd, ef, Wo, bo, gamma, beta, outf);
}

// Round 2
// 690.393 us; speedup vs baseline: 1.4610x; 1.4610x over previous
//
#include <hip/hip_runtime.h>
#include <math.h>

#define E_N   8192
#define HID   128
#define NRAD  64
#define KNB   32
#define CUTF  10.0f
#define LNEPS 1e-5f

typedef unsigned short u16;
typedef __bf16 bf16x8 __attribute__((ext_vector_type(8)));
typedef u16    u16x8  __attribute__((ext_vector_type(8)));
typedef float  f32x4  __attribute__((ext_vector_type(4)));

__device__ __forceinline__ u16 f2bf(float f) {
  unsigned u = __float_as_uint(f);
  unsigned r = (u + 0x7fffu + ((u >> 16) & 1u)) >> 16;   // RNE
  return (u16)r;
}

__device__ __forceinline__ unsigned long long shflx64(unsigned long long v, int m) {
  int lo = __shfl_xor((int)(v & 0xffffffffull), m, 64);
  int hi = __shfl_xor((int)(v >> 32), m, 64);
  return ((unsigned long long)(unsigned)hi << 32) | (unsigned)lo;
}

__device__ __forceinline__ unsigned long long d2key(float v, int j) {
  unsigned u = __float_as_uint(v);
  u = (u & 0x80000000u) ? ~u : (u | 0x80000000u);
  return ((unsigned long long)u << 32) | (unsigned)j;
}

// ---------------- kernel 0: convert W1/W2 to bf16, transposed [col][k] ----------------
__global__ void k_convw(const float* __restrict__ W1, const float* __restrict__ W2,
                        u16* __restrict__ Wt1, u16* __restrict__ Wt2) {
  int b = blockIdx.x;            // output col 0..127
  int t = threadIdx.x;           // 0..447
  if (t < 320)      Wt1[b*320 + t]        = f2bf(W1[t*HID + b]);
  else if (t < 448) Wt2[b*HID + (t-320)]  = f2bf(W2[(t-320)*HID + b]);
}

// ---------------- kernel 1: edge centers + squared norms ----------------
__global__ void k_prep(const float* __restrict__ nc, const int* __restrict__ ei,
                       float* __restrict__ cen, float* __restrict__ n2) {
  int e = blockIdx.x * 256 + threadIdx.x;
  if (e >= E_N) return;
  int a = ei[e], b = ei[E_N + e];
  float x = (nc[a*3+0] + nc[b*3+0]) * 0.5f;
  float y = (nc[a*3+1] + nc[b*3+1]) * 0.5f;
  float z = (nc[a*3+2] + nc[b*3+2]) * 0.5f;
  cen[e*3+0] = x; cen[e*3+1] = y; cen[e*3+2] = z;
  n2[e] = x*x + y*y + z*z;
}

// ---------------- kernel 2: top-K nearest edge centers ----------------
__global__ __launch_bounds__(256) void k_topk(const float* __restrict__ cen,
    const float* __restrict__ n2, int* __restrict__ idxo) {
  const int row = blockIdx.x;
  const int t = threadIdx.x;
  const float cx = cen[row*3+0], cy = cen[row*3+1], cz = cen[row*3+2];
  const float n2i = n2[row];
  float vals[32];
  #pragma unroll
  for (int s = 0; s < 32; ++s) {
    int j = t + (s << 8);
    float dot = cx*cen[j*3+0] + cy*cen[j*3+1] + cz*cen[j*3+2];
    vals[s] = (n2i + n2[j]) - 2.0f*dot;
  }
  unsigned long long lk = d2key(vals[0], t);
  #pragma unroll
  for (int s = 1; s < 32; ++s) {
    unsigned long long kk = d2key(vals[s], t + (s << 8));
    lk = kk < lk ? kk : lk;
  }
  __shared__ unsigned long long wmin[4];
  __shared__ unsigned long long winner;
  for (int kk = 0; kk < KNB; ++kk) {
    unsigned long long r = lk;
    #pragma unroll
    for (int m = 1; m < 64; m <<= 1) {
      unsigned long long o = shflx64(r, m);
      r = o < r ? o : r;
    }
    if ((t & 63) == 0) wmin[t >> 6] = r;
    __syncthreads();
    if (t == 0) {
      unsigned long long w0 = wmin[0];
      if (wmin[1] < w0) w0 = wmin[1];
      if (wmin[2] < w0) w0 = wmin[2];
      if (wmin[3] < w0) w0 = wmin[3];
      winner = w0;
      idxo[row*KNB + kk] = (int)(w0 & 0xffffffffu);
    }
    __syncthreads();
    int jw = (int)(winner & 0xffffffffu);
    if ((jw & 255) == t) {
      int sw = jw >> 8;
      #pragma unroll
      for (int s = 0; s < 32; ++s) if (s == sw) vals[s] = __uint_as_float(0x7f800000u);
      lk = d2key(vals[0], t);
      #pragma unroll
      for (int s = 1; s < 32; ++s) {
        unsigned long long kk2 = d2key(vals[s], t + (s << 8));
        lk = kk2 < lk ? kk2 : lk;
      }
    }
  }
}

// ---------------- kernel 3: q,k,v projections + coordinate gates ----------------
__global__ void k_qkv_gates(const float* __restrict__ ef,
    const float* __restrict__ Wq, const float* __restrict__ Wk, const float* __restrict__ Wv,
    const float* __restrict__ Wg1, const float* __restrict__ bg1,
    const float* __restrict__ Wg2, const float* __restrict__ bg2,
    float* __restrict__ qf, float* __restrict__ kf, float* __restrict__ vf,
    float* __restrict__ gates) {
  int e = blockIdx.x, o = threadIdx.x;   // 128 threads
  __shared__ float efs[HID];
  __shared__ float vs[HID];
  __shared__ float red[2];
  efs[o] = ef[e*HID + o];
  __syncthreads();
  float aq = 0.f, ak = 0.f, av = 0.f;
  #pragma unroll 8
  for (int d = 0; d < HID; ++d) {
    float a = efs[d];
    aq = fmaf(a, Wq[d*HID + o], aq);
    ak = fmaf(a, Wk[d*HID + o], ak);
    av = fmaf(a, Wv[d*HID + o], av);
  }
  qf[e*HID + o] = aq; kf[e*HID + o] = ak; vf[e*HID + o] = av;
  vs[o] = av;
  __syncthreads();
  float g = 0.f;
  #pragma unroll 8
  for (int d = 0; d < HID; ++d) g = fmaf(vs[d], Wg1[d*HID + o], g);
  g += bg1[o];
  g = g / (1.0f + expf(-g));            // silu
  float part = g * Wg2[o];
  #pragma unroll
  for (int m = 1; m < 64; m <<= 1) part += __shfl_xor(part, m, 64);
  if ((o & 63) == 0) red[o >> 6] = part;
  __syncthreads();
  if (o == 0) {
    float s = red[0] + red[1] + bg2[0];
    gates[e] = 1.0f / (1.0f + expf(-s));
  }
}

// ---------------- kernel 4: per-pair geometry + q.k dot ----------------
__global__ void k_geom(const float* __restrict__ cen, const int* __restrict__ idx,
    const float* __restrict__ qf, const float* __restrict__ kf,
    float* __restrict__ dist, float* __restrict__ cdiff, float* __restrict__ dotv) {
  int p = blockIdx.x * 4 + (threadIdx.x >> 6);
  int lane = threadIdx.x & 63;
  int e = p >> 5;
  int j = idx[p];
  float s = qf[e*HID + lane] * kf[j*HID + lane]
          + qf[e*HID + 64 + lane] * kf[j*HID + 64 + lane];
  #pragma unroll
  for (int m = 1; m < 64; m <<= 1) s += __shfl_xor(s, m, 64);
  if (lane == 0) {
    dotv[p] = s;
    float dx = cen[e*3+0] - cen[j*3+0];
    float dy = cen[e*3+1] - cen[j*3+1];
    float dz = cen[e*3+2] - cen[j*3+2];
    dist[p] = sqrtf(dx*dx + dy*dy + dz*dz);
    cdiff[p*3+0] = dx; cdiff[p*3+1] = dy; cdiff[p*3+2] = dz;
  }
}

// ---------------- kernel 5: fused attention MLP -> scores (bf16 MFMA) ----------------
// 64 rows/block, 4 waves; wave w owns cols [w*32, w*32+32).
// acc[4 row-tiles][2 col-tiles] of 16x16x32 MFMA; A staged bf16+XOR-swizzled LDS;
// B = pre-transposed bf16 weights read straight from global (L2-resident).
__global__ __launch_bounds__(256) void k_mlp(
    const float* __restrict__ qf, const float* __restrict__ kf,
    const int* __restrict__ idx, const float* __restrict__ dist,
    const float* __restrict__ dotv,
    const u16* __restrict__ Wt1, const u16* __restrict__ Wt2,
    const float* __restrict__ W1, const float* __restrict__ b1,
    const float* __restrict__ b2, const float* __restrict__ W3,
    const float* __restrict__ b3,
    const float* __restrict__ centers, const float* __restrict__ widths,
    float* __restrict__ scores) {
  __shared__ u16 sH[64*128];      // 16 KiB; first 8 KiB doubles as the A-chunk buffer
  __shared__ float spart[4][64];  // per-wave partial raw scores

  const int t  = threadIdx.x;
  const int w  = t >> 6, l = t & 63;
  const int l15 = l & 15, l4 = l >> 4;
  const int rowbase = blockIdx.x * 64;

  // staging mapping: thread covers row (t>>2), k-quarter (t&3) of the 64-wide chunk
  const int srow = t >> 2, sb = t & 3;
  const int sp = rowbase + srow;
  const int se = sp >> 5;
  const int sj = idx[sp];
  const float sdist = dist[sp];
  const float sincut = (sdist <= CUTF) ? 1.0f : 0.0f;

  f32x4 acc[4][2];
  #pragma unroll
  for (int rt = 0; rt < 4; ++rt)
    #pragma unroll
    for (int ct = 0; ct < 2; ++ct) acc[rt][ct] = (f32x4){0.f,0.f,0.f,0.f};

  // -------- GEMM1: K-chunks of 64 over [q | k_j | rbf] --------
  for (int c = 0; c < 5; ++c) {
    u16 tmp[16];
    if (c < 4) {
      const float* src = (c < 2) ? (qf + se*HID + c*64) : (kf + sj*HID + (c-2)*64);
      #pragma unroll
      for (int i4 = 0; i4 < 4; ++i4) {
        float4 vv = *(const float4*)(src + sb*16 + i4*4);
        tmp[i4*4+0] = f2bf(vv.x); tmp[i4*4+1] = f2bf(vv.y);
        tmp[i4*4+2] = f2bf(vv.z); tmp[i4*4+3] = f2bf(vv.w);
      }
    } else {
      #pragma unroll
      for (int i4 = 0; i4 < 4; ++i4) {
        float4 cc = *(const float4*)(centers + sb*16 + i4*4);
        float4 ww = *(const float4*)(widths  + sb*16 + i4*4);
        float c4[4] = {cc.x,cc.y,cc.z,cc.w}, w4[4] = {ww.x,ww.y,ww.z,ww.w};
        #pragma unroll
        for (int jj = 0; jj < 4; ++jj) {
          float df = sdist - c4[jj];
          tmp[i4*4+jj] = f2bf(expf(-w4[jj]*df*df) * sincut);
        }
      }
    }
    #pragma unroll
    for (int g = 0; g < 2; ++g) {
      u16x8 vv;
      #pragma unroll
      for (int jj = 0; jj < 8; ++jj) vv[jj] = tmp[g*8+jj];
      int widx = (srow*64 + sb*16 + g*8) ^ ((srow & 7) << 3);
      *(u16x8*)(&sH[widx]) = vv;
    }
    __syncthreads();
    #pragma unroll
    for (int ks = 0; ks < 2; ++ks) {
      bf16x8 af[4], bfr[2];
      #pragma unroll
      for (int rt = 0; rt < 4; ++rt) {
        int row = rt*16 + l15;
        int aidx = (row*64 + ks*32 + l4*8) ^ ((row & 7) << 3);
        af[rt] = *(const bf16x8*)(&sH[aidx]);
      }
      #pragma unroll
      for (int ct = 0; ct < 2; ++ct) {
        int col = w*32 + ct*16 + l15;
        bfr[ct] = *(const bf16x8*)(&Wt1[col*320 + c*64 + ks*32 + l4*8]);
      }
      #pragma unroll
      for (int rt = 0; rt < 4; ++rt)
        #pragma unroll
        for (int ct = 0; ct < 2; ++ct)
          acc[rt][ct] = __builtin_amdgcn_mfma_f32_16x16x32_bf16(af[rt], bfr[ct], acc[rt][ct], 0, 0, 0);
    }
    __syncthreads();
  }

  // -------- epilogue 1: + dot*W1[320] + b1, silu, h -> LDS bf16 (swizzled) --------
  {
    float w320[2], b1r[2];
    #pragma unroll
    for (int ct = 0; ct < 2; ++ct) {
      int col = w*32 + ct*16 + l15;
      w320[ct] = W1[320*HID + col]; b1r[ct] = b1[col];
    }
    #pragma unroll
    for (int rt = 0; rt < 4; ++rt) {
      #pragma unroll
      for (int r = 0; r < 4; ++r) {
        int row = rt*16 + l4*4 + r;
        float dv = dotv[rowbase + row];
        #pragma unroll
        for (int ct = 0; ct < 2; ++ct) {
          int col = w*32 + ct*16 + l15;
          float x = acc[rt][ct][r] + dv*w320[ct] + b1r[ct];
          float h = x / (1.0f + expf(-x));
          sH[(row*128 + col) ^ ((row & 7) << 3)] = f2bf(h);
        }
      }
    }
  }
  __syncthreads();

  #pragma unroll
  for (int rt = 0; rt < 4; ++rt)
    #pragma unroll
    for (int ct = 0; ct < 2; ++ct) acc[rt][ct] = (f32x4){0.f,0.f,0.f,0.f};

  // -------- GEMM2: h @ W2 --------
  #pragma unroll
  for (int ks = 0; ks < 4; ++ks) {
    bf16x8 af[4], bfr[2];
    #pragma unroll
    for (int rt = 0; rt < 4; ++rt) {
      int row = rt*16 + l15;
      int aidx = (row*128 + ks*32 + l4*8) ^ ((row & 7) << 3);
      af[rt] = *(const bf16x8*)(&sH[aidx]);
    }
    #pragma unroll
    for (int ct = 0; ct < 2; ++ct) {
      int col = w*32 + ct*16 + l15;
      bfr[ct] = *(const bf16x8*)(&Wt2[col*128 + ks*32 + l4*8]);
    }
    #pragma unroll
    for (int rt = 0; rt < 4; ++rt)
      #pragma unroll
      for (int ct = 0; ct < 2; ++ct)
        acc[rt][ct] = __builtin_amdgcn_mfma_f32_16x16x32_bf16(af[rt], bfr[ct], acc[rt][ct], 0, 0, 0);
  }

  // -------- epilogue 2: silu, dot with W3, reduce 32 cols -> per-wave partial --------
  {
    float b2r[2], w3r[2];
    #pragma unroll
    for (int ct = 0; ct < 2; ++ct) {
      int col = w*32 + ct*16 + l15;
      b2r[ct] = b2[col]; w3r[ct] = W3[col];
    }
    #pragma unroll
    for (int rt = 0; rt < 4; ++rt) {
      #pragma unroll
      for (int r = 0; r < 4; ++r) {
        float part = 0.f;
        #pragma unroll
        for (int ct = 0; ct < 2; ++ct) {
          float x = acc[rt][ct][r] + b2r[ct];
          float h = x / (1.0f + expf(-x));
          part = fmaf(h, w3r[ct], part);
        }
        part += __shfl_xor(part, 1, 64);
        part += __shfl_xor(part, 2, 64);
        part += __shfl_xor(part, 4, 64);
        part += __shfl_xor(part, 8, 64);
        if (l15 == 0) spart[w][rt*16 + l4*4 + r] = part;
      }
    }
  }
  __syncthreads();
  if (t < 64) {
    int p = rowbase + t;
    float raw = spart[0][t] + spart[1][t] + spart[2][t] + spart[3][t] + b3[0];
    scores[p] = (dist[p] <= CUTF) ? raw : 0.0f;
  }
}

// ---------------- kernel 6: softmax + weighted V + coord update ----------------
__global__ void k_combine(const float* __restrict__ scores, const int* __restrict__ idx,
    const float* __restrict__ vf, const float* __restrict__ gates,
    const float* __restrict__ cdiff, const float* __restrict__ ef,
    const float* __restrict__ ec, float* __restrict__ upd, float* __restrict__ outc) {
  int e = blockIdx.x, t = threadIdx.x;   // 128 threads
  __shared__ float wk[KNB], wg[KNB];
  __shared__ int jj[KNB];
  if (t < 64) {
    float sc = (t < KNB) ? scores[e*KNB + t] : -1e30f;
    float m = sc;
    #pragma unroll
    for (int mm = 1; mm < 32; mm <<= 1) m = fmaxf(m, __shfl_xor(m, mm, 64));
    m = fmaxf(m, 0.0f);
    float ex = (t < KNB) ? expf(sc - m) : 0.0f;
    float Z = ex;
    #pragma unroll
    for (int mm = 1; mm < 32; mm <<= 1) Z += __shfl_xor(Z, mm, 64);
    Z += 8160.0f * expf(-m);             // (E-K) zero-score tail
    if (t < KNB) {
      float w = ex / Z;
      int j = idx[e*KNB + t];
      jj[t] = j; wk[t] = w; wg[t] = w * gates[j];
    }
  }
  __syncthreads();
  float acc = 0.0f;
  #pragma unroll 4
  for (int kk = 0; kk < KNB; ++kk) acc = fmaf(wk[kk], vf[jj[kk]*HID + t], acc);
  upd[e*HID + t] = ef[e*HID + t] + acc;
  if (t < 3) {
    float csum = 0.0f;
    #pragma unroll 4
    for (int kk = 0; kk < KNB; ++kk) csum = fmaf(wg[kk], cdiff[(e*KNB + kk)*3 + t], csum);
    outc[e*3 + t] = ec[e*3 + t] + csum;
  }
}

// ---------------- kernel 7: output projection + residual + LayerNorm ----------------
__global__ void k_out(const float* __restrict__ upd, const float* __restrict__ ef,
    const float* __restrict__ Wo, const float* __restrict__ bo,
    const float* __restrict__ gamma, const float* __restrict__ beta,
    float* __restrict__ outf) {
  int e = blockIdx.x, o = threadIdx.x;   // 128 threads
  __shared__ float us[HID];
  __shared__ float red2[2];
  us[o] = upd[e*HID + o];
  __syncthreads();
  float a = 0.0f;
  #pragma unroll 8
  for (int d = 0; d < HID; ++d) a = fmaf(us[d], Wo[d*HID + o], a);
  float x = ef[e*HID + o] + a + bo[o];
  float s = x;
  #pragma unroll
  for (int m = 1; m < 64; m <<= 1) s += __shfl_xor(s, m, 64);
  if ((o & 63) == 0) red2[o >> 6] = s;
  __syncthreads();
  float mu = (red2[0] + red2[1]) * (1.0f/128.0f);
  __syncthreads();
  float dv = x - mu;
  float s2 = dv*dv;
  #pragma unroll
  for (int m = 1; m < 64; m <<= 1) s2 += __shfl_xor(s2, m, 64);
  if ((o & 63) == 0) red2[o >> 6] = s2;
  __syncthreads();
  float var = (red2[0] + red2[1]) * (1.0f/128.0f);
  outf[e*HID + o] = dv * rsqrtf(var + LNEPS) * gamma[o] + beta[o];
}

extern "C" void kernel_launch(void* const* d_in, const int* in_sizes, int n_in,
                              void* d_out, int out_size, void* d_ws, size_t ws_size,
                              hipStream_t stream) {
  const float* ef   = (const float*)d_in[0];
  const float* ec   = (const float*)d_in[1];
  const float* nc   = (const float*)d_in[2];
  const float* Wq   = (const float*)d_in[3];
  const float* Wk   = (const float*)d_in[4];
  const float* Wv   = (const float*)d_in[5];
  const float* W1   = (const float*)d_in[6];
  const float* b1   = (const float*)d_in[7];
  const float* W2   = (const float*)d_in[8];
  const float* b2   = (const float*)d_in[9];
  const float* W3   = (const float*)d_in[10];
  const float* b3   = (const float*)d_in[11];
  const float* Wg1  = (const float*)d_in[12];
  const float* bg1  = (const float*)d_in[13];
  const float* Wg2  = (const float*)d_in[14];
  const float* bg2  = (const float*)d_in[15];
  const float* Wo   = (const float*)d_in[16];
  const float* bo   = (const float*)d_in[17];
  const float* gamma= (const float*)d_in[18];
  const float* beta = (const float*)d_in[19];
  const float* centers = (const float*)d_in[20];
  const float* widths  = (const float*)d_in[21];
  const int*   eidx    = (const int*)d_in[22];

  float* outf = (float*)d_out;
  float* outc = outf + (size_t)E_N * HID;

  float* cen   = (float*)d_ws;
  float* n2    = cen + 3*E_N;
  int*   idx   = (int*)(n2 + E_N);
  float* dist  = (float*)(idx + E_N*KNB);
  float* cdiff = dist + E_N*KNB;
  float* dotv  = cdiff + 3*E_N*KNB;
  float* qf    = dotv + E_N*KNB;
  float* kf    = qf + (size_t)E_N*HID;
  float* vf    = kf + (size_t)E_N*HID;
  float* scores= vf + (size_t)E_N*HID;
  float* gates = scores + E_N*KNB;
  float* upd   = gates + E_N;
  u16*   Wt1   = (u16*)(upd + (size_t)E_N*HID);   // 128*320 bf16
  u16*   Wt2   = Wt1 + 128*320;                   // 128*128 bf16

  k_convw<<<128, 448, 0, stream>>>(W1, W2, Wt1, Wt2);
  k_prep<<<E_N/256, 256, 0, stream>>>(nc, eidx, cen, n2);
  k_topk<<<E_N, 256, 0, stream>>>(cen, n2, idx);
  k_qkv_gates<<<E_N, 128, 0, stream>>>(ef, Wq, Wk, Wv, Wg1, bg1, Wg2, bg2, qf, kf, vf, gates);
  k_geom<<<E_N*KNB/4, 256, 0, stream>>>(cen, idx, qf, kf, dist, cdiff, dotv);
  k_mlp<<<E_N*KNB/64, 256, 0, stream>>>(qf, kf, idx, dist, dotv, Wt1, Wt2,
                                        W1, b1, b2, W3, b3, centers, widths, scores);
  k_combine<<<E_N, 128, 0, stream>>>(scores, idx, vf, gates, cdiff, ef, ec, upd, outc);
  k_out<<<E_N, 128, 0, stream>>>(upd, ef, Wo, bo, gamma, beta, outf);
}

// Round 3
// 379.162 us; speedup vs baseline: 2.6602x; 1.8208x over previous
//
#include <hip/hip_runtime.h>
#include <math.h>

#define E_N   8192
#define HID   128
#define NRAD  64
#define KNB   32
#define CUTF  10.0f
#define LNEPS 1e-5f

typedef unsigned short u16;
typedef unsigned int   u32;
typedef __bf16 bf16x8 __attribute__((ext_vector_type(8)));
typedef u16    u16x8  __attribute__((ext_vector_type(8)));
typedef float  f32x4  __attribute__((ext_vector_type(4)));

__device__ __forceinline__ u16 f2bf(float f) {
  unsigned u = __float_as_uint(f);
  unsigned r = (u + 0x7fffu + ((u >> 16) & 1u)) >> 16;   // RNE
  return (u16)r;
}

// ---------------- kernel 0: convert W1/W2 to bf16, transposed [col][k] ----------------
__global__ void k_convw(const float* __restrict__ W1, const float* __restrict__ W2,
                        u16* __restrict__ Wt1, u16* __restrict__ Wt2) {
  int b = blockIdx.x;            // output col 0..127
  int t = threadIdx.x;           // 0..447
  if (t < 320)      Wt1[b*320 + t]        = f2bf(W1[t*HID + b]);
  else if (t < 448) Wt2[b*HID + (t-320)]  = f2bf(W2[(t-320)*HID + b]);
}

// ---------------- kernel 1: edge centers + squared norms (packed float4) ----------------
__global__ void k_prep(const float* __restrict__ nc, const int* __restrict__ ei,
                       float4* __restrict__ cen4) {
  int e = blockIdx.x * 256 + threadIdx.x;
  if (e >= E_N) return;
  int a = ei[e], b = ei[E_N + e];
  float x = (nc[a*3+0] + nc[b*3+0]) * 0.5f;
  float y = (nc[a*3+1] + nc[b*3+1]) * 0.5f;
  float z = (nc[a*3+2] + nc[b*3+2]) * 0.5f;
  cen4[e] = make_float4(x, y, z, x*x + y*y + z*z);
}

// ---------------- kernel 2: top-K via 3-level radix select ----------------
// One block (256 thr) per row. Keys: monotone-u32 of d2, ties by candidate index.
// Downstream sums over the K slots are permutation-invariant, so the output
// set is emitted unordered (atomic slots), ties by smallest index like
// jax.lax.top_k's stable ordering.
__global__ __launch_bounds__(256) void k_topk(const float4* __restrict__ cen4,
                                              int* __restrict__ idxo) {
  const int row = blockIdx.x;
  const int t = threadIdx.x;
  const int lane = t & 63, w = t >> 6;
  __shared__ u32 hist[2048];
  __shared__ u32 red[4];
  __shared__ u32 bc_bin, bc_cless, bc_min, selc;

  const float4 me = cen4[row];
  u32 keys[32];
  #pragma unroll
  for (int s = 0; s < 32; ++s) {
    int j = t + (s << 8);
    float4 c = cen4[j];
    float dot = me.x*c.x + me.y*c.y + me.z*c.z;
    float d2 = (me.w + c.w) - 2.0f*dot;       // same expression as reference gram trick
    unsigned u = __float_as_uint(d2);
    keys[s] = (u & 0x80000000u) ? ~u : (u | 0x80000000u);
  }

  u32 want = 0, mask = 0;
  int need = KNB;
  u32 c_less = 0;

  #pragma unroll 1
  for (int lev = 0; lev < 3; ++lev) {
    const int sh = (lev == 0) ? 21 : (lev == 1) ? 10 : 0;
    const u32 bm = (lev == 2) ? 0x3FFu : 0x7FFu;

    for (int i = t; i < 2048; i += 256) hist[i] = 0;
    __syncthreads();
    #pragma unroll
    for (int s = 0; s < 32; ++s)
      if ((keys[s] & mask) == want)
        atomicAdd(&hist[(keys[s] >> sh) & bm], 1u);
    __syncthreads();

    // per-thread partial over bins [t*8, t*8+8)
    u32 h8[8]; u32 p = 0;
    #pragma unroll
    for (int b = 0; b < 8; ++b) { h8[b] = hist[t*8 + b]; p += h8[b]; }
    // wave inclusive scan (counts < 2^31, int shfl safe)
    int inc = (int)p;
    #pragma unroll
    for (int off = 1; off < 64; off <<= 1) {
      int v = __shfl_up(inc, off, 64);
      if (lane >= off) inc += v;
    }
    if (lane == 63) red[w] = (u32)inc;
    __syncthreads();
    u32 woff = 0;
    #pragma unroll
    for (int ww = 0; ww < 4; ++ww) woff += (ww < w) ? red[ww] : 0u;
    u32 cum = woff + (u32)inc - p;            // exclusive prefix at bin t*8
    #pragma unroll
    for (int b = 0; b < 8; ++b) {
      if (cum < (u32)need && cum + h8[b] >= (u32)need) {
        bc_bin = (u32)(t*8 + b); bc_cless = cum;
      }
      cum += h8[b];
    }
    __syncthreads();
    u32 binId = bc_bin, cb = bc_cless;
    c_less += cb;
    need  -= (int)cb;
    want  |= binId << sh;
    mask  |= bm << sh;
    __syncthreads();
  }

  const u32 T = want;                          // exact key of the rank-32 boundary
  if (t == 0) selc = 0;
  __syncthreads();
  #pragma unroll
  for (int s = 0; s < 32; ++s) {
    if (keys[s] < T) {
      u32 pos = atomicAdd(&selc, 1u);
      idxo[row*KNB + pos] = t + (s << 8);
    }
  }
  // ties at T: take `need` smallest indices (matches stable top_k)
  for (int r = 0; r < need; ++r) {
    u32 lm = 0xFFFFFFFFu;
    #pragma unroll
    for (int s = 0; s < 32; ++s)
      if (keys[s] == T) { u32 j = (u32)(t + (s << 8)); lm = j < lm ? j : lm; }
    #pragma unroll
    for (int off = 1; off < 64; off <<= 1) {
      u32 o = (u32)__shfl_xor((int)lm, off, 64);
      lm = o < lm ? o : lm;
    }
    if (lane == 0) red[w] = lm;
    __syncthreads();
    if (t == 0) {
      u32 m0 = red[0] < red[1] ? red[0] : red[1];
      u32 m1 = red[2] < red[3] ? red[2] : red[3];
      u32 m = m0 < m1 ? m0 : m1;
      bc_min = m;
      idxo[row*KNB + (int)c_less + r] = (int)m;
    }
    __syncthreads();
    u32 jw = bc_min;
    if ((jw & 255u) == (u32)t) keys[jw >> 8] = 0xFFFFFFFFu;
  }
}

// ---------------- kernel 3: q,k,v projections + coordinate gates ----------------
__global__ void k_qkv_gates(const float* __restrict__ ef,
    const float* __restrict__ Wq, const float* __restrict__ Wk, const float* __restrict__ Wv,
    const float* __restrict__ Wg1, const float* __restrict__ bg1,
    const float* __restrict__ Wg2, const float* __restrict__ bg2,
    float* __restrict__ qf, float* __restrict__ kf, float* __restrict__ vf,
    float* __restrict__ gates) {
  int e = blockIdx.x, o = threadIdx.x;   // 128 threads
  __shared__ float efs[HID];
  __shared__ float vs[HID];
  __shared__ float red[2];
  efs[o] = ef[e*HID + o];
  __syncthreads();
  float aq = 0.f, ak = 0.f, av = 0.f;
  #pragma unroll 8
  for (int d = 0; d < HID; ++d) {
    float a = efs[d];
    aq = fmaf(a, Wq[d*HID + o], aq);
    ak = fmaf(a, Wk[d*HID + o], ak);
    av = fmaf(a, Wv[d*HID + o], av);
  }
  qf[e*HID + o] = aq; kf[e*HID + o] = ak; vf[e*HID + o] = av;
  vs[o] = av;
  __syncthreads();
  float g = 0.f;
  #pragma unroll 8
  for (int d = 0; d < HID; ++d) g = fmaf(vs[d], Wg1[d*HID + o], g);
  g += bg1[o];
  g = g / (1.0f + expf(-g));            // silu
  float part = g * Wg2[o];
  #pragma unroll
  for (int m = 1; m < 64; m <<= 1) part += __shfl_xor(part, m, 64);
  if ((o & 63) == 0) red[o >> 6] = part;
  __syncthreads();
  if (o == 0) {
    float s = red[0] + red[1] + bg2[0];
    gates[e] = 1.0f / (1.0f + expf(-s));
  }
}

// ---------------- kernel 4: per-pair geometry + q.k dot ----------------
__global__ void k_geom(const float4* __restrict__ cen4, const int* __restrict__ idx,
    const float* __restrict__ qf, const float* __restrict__ kf,
    float* __restrict__ dist, float* __restrict__ cdiff, float* __restrict__ dotv) {
  int p = blockIdx.x * 4 + (threadIdx.x >> 6);
  int lane = threadIdx.x & 63;
  int e = p >> 5;
  int j = idx[p];
  float s = qf[e*HID + lane] * kf[j*HID + lane]
          + qf[e*HID + 64 + lane] * kf[j*HID + 64 + lane];
  #pragma unroll
  for (int m = 1; m < 64; m <<= 1) s += __shfl_xor(s, m, 64);
  if (lane == 0) {
    dotv[p] = s;
    float4 ce = cen4[e], cj = cen4[j];
    float dx = ce.x - cj.x;
    float dy = ce.y - cj.y;
    float dz = ce.z - cj.z;
    dist[p] = sqrtf(dx*dx + dy*dy + dz*dz);
    cdiff[p*3+0] = dx; cdiff[p*3+1] = dy; cdiff[p*3+2] = dz;
  }
}

// ---------------- kernel 5: fused attention MLP -> scores (bf16 MFMA) ----------------
__global__ __launch_bounds__(256) void k_mlp(
    const float* __restrict__ qf, const float* __restrict__ kf,
    const int* __restrict__ idx, const float* __restrict__ dist,
    const float* __restrict__ dotv,
    const u16* __restrict__ Wt1, const u16* __restrict__ Wt2,
    const float* __restrict__ W1, const float* __restrict__ b1,
    const float* __restrict__ b2, const float* __restrict__ W3,
    const float* __restrict__ b3,
    const float* __restrict__ centers, const float* __restrict__ widths,
    float* __restrict__ scores) {
  __shared__ u16 sH[64*128];      // 16 KiB; first 8 KiB doubles as the A-chunk buffer
  __shared__ float spart[4][64];  // per-wave partial raw scores

  const int t  = threadIdx.x;
  const int w  = t >> 6, l = t & 63;
  const int l15 = l & 15, l4 = l >> 4;
  const int rowbase = blockIdx.x * 64;

  const int srow = t >> 2, sb = t & 3;
  const int sp = rowbase + srow;
  const int se = sp >> 5;
  const int sj = idx[sp];
  const float sdist = dist[sp];
  const float sincut = (sdist <= CUTF) ? 1.0f : 0.0f;

  f32x4 acc[4][2];
  #pragma unroll
  for (int rt = 0; rt < 4; ++rt)
    #pragma unroll
    for (int ct = 0; ct < 2; ++ct) acc[rt][ct] = (f32x4){0.f,0.f,0.f,0.f};

  // -------- GEMM1: K-chunks of 64 over [q | k_j | rbf] --------
  for (int c = 0; c < 5; ++c) {
    u16 tmp[16];
    if (c < 4) {
      const float* src = (c < 2) ? (qf + se*HID + c*64) : (kf + sj*HID + (c-2)*64);
      #pragma unroll
      for (int i4 = 0; i4 < 4; ++i4) {
        float4 vv = *(const float4*)(src + sb*16 + i4*4);
        tmp[i4*4+0] = f2bf(vv.x); tmp[i4*4+1] = f2bf(vv.y);
        tmp[i4*4+2] = f2bf(vv.z); tmp[i4*4+3] = f2bf(vv.w);
      }
    } else {
      #pragma unroll
      for (int i4 = 0; i4 < 4; ++i4) {
        float4 cc = *(const float4*)(centers + sb*16 + i4*4);
        float4 ww = *(const float4*)(widths  + sb*16 + i4*4);
        float c4[4] = {cc.x,cc.y,cc.z,cc.w}, w4[4] = {ww.x,ww.y,ww.z,ww.w};
        #pragma unroll
        for (int jj = 0; jj < 4; ++jj) {
          float df = sdist - c4[jj];
          tmp[i4*4+jj] = f2bf(expf(-w4[jj]*df*df) * sincut);
        }
      }
    }
    #pragma unroll
    for (int g = 0; g < 2; ++g) {
      u16x8 vv;
      #pragma unroll
      for (int jj = 0; jj < 8; ++jj) vv[jj] = tmp[g*8+jj];
      int widx = (srow*64 + sb*16 + g*8) ^ ((srow & 7) << 3);
      *(u16x8*)(&sH[widx]) = vv;
    }
    __syncthreads();
    #pragma unroll
    for (int ks = 0; ks < 2; ++ks) {
      bf16x8 af[4], bfr[2];
      #pragma unroll
      for (int rt = 0; rt < 4; ++rt) {
        int row = rt*16 + l15;
        int aidx = (row*64 + ks*32 + l4*8) ^ ((row & 7) << 3);
        af[rt] = *(const bf16x8*)(&sH[aidx]);
      }
      #pragma unroll
      for (int ct = 0; ct < 2; ++ct) {
        int col = w*32 + ct*16 + l15;
        bfr[ct] = *(const bf16x8*)(&Wt1[col*320 + c*64 + ks*32 + l4*8]);
      }
      #pragma unroll
      for (int rt = 0; rt < 4; ++rt)
        #pragma unroll
        for (int ct = 0; ct < 2; ++ct)
          acc[rt][ct] = __builtin_amdgcn_mfma_f32_16x16x32_bf16(af[rt], bfr[ct], acc[rt][ct], 0, 0, 0);
    }
    __syncthreads();
  }

  // -------- epilogue 1: + dot*W1[320] + b1, silu, h -> LDS bf16 (swizzled) --------
  {
    float w320[2], b1r[2];
    #pragma unroll
    for (int ct = 0; ct < 2; ++ct) {
      int col = w*32 + ct*16 + l15;
      w320[ct] = W1[320*HID + col]; b1r[ct] = b1[col];
    }
    #pragma unroll
    for (int rt = 0; rt < 4; ++rt) {
      #pragma unroll
      for (int r = 0; r < 4; ++r) {
        int row = rt*16 + l4*4 + r;
        float dv = dotv[rowbase + row];
        #pragma unroll
        for (int ct = 0; ct < 2; ++ct) {
          int col = w*32 + ct*16 + l15;
          float x = acc[rt][ct][r] + dv*w320[ct] + b1r[ct];
          float h = x / (1.0f + expf(-x));
          sH[(row*128 + col) ^ ((row & 7) << 3)] = f2bf(h);
        }
      }
    }
  }
  __syncthreads();

  #pragma unroll
  for (int rt = 0; rt < 4; ++rt)
    #pragma unroll
    for (int ct = 0; ct < 2; ++ct) acc[rt][ct] = (f32x4){0.f,0.f,0.f,0.f};

  // -------- GEMM2: h @ W2 --------
  #pragma unroll
  for (int ks = 0; ks < 4; ++ks) {
    bf16x8 af[4], bfr[2];
    #pragma unroll
    for (int rt = 0; rt < 4; ++rt) {
      int row = rt*16 + l15;
      int aidx = (row*128 + ks*32 + l4*8) ^ ((row & 7) << 3);
      af[rt] = *(const bf16x8*)(&sH[aidx]);
    }
    #pragma unroll
    for (int ct = 0; ct < 2; ++ct) {
      int col = w*32 + ct*16 + l15;
      bfr[ct] = *(const bf16x8*)(&Wt2[col*128 + ks*32 + l4*8]);
    }
    #pragma unroll
    for (int rt = 0; rt < 4; ++rt)
      #pragma unroll
      for (int ct = 0; ct < 2; ++ct)
        acc[rt][ct] = __builtin_amdgcn_mfma_f32_16x16x32_bf16(af[rt], bfr[ct], acc[rt][ct], 0, 0, 0);
  }

  // -------- epilogue 2: silu, dot with W3, reduce 32 cols -> per-wave partial --------
  {
    float b2r[2], w3r[2];
    #pragma unroll
    for (int ct = 0; ct < 2; ++ct) {
      int col = w*32 + ct*16 + l15;
      b2r[ct] = b2[col]; w3r[ct] = W3[col];
    }
    #pragma unroll
    for (int rt = 0; rt < 4; ++rt) {
      #pragma unroll
      for (int r = 0; r < 4; ++r) {
        float part = 0.f;
        #pragma unroll
        for (int ct = 0; ct < 2; ++ct) {
          float x = acc[rt][ct][r] + b2r[ct];
          float h = x / (1.0f + expf(-x));
          part = fmaf(h, w3r[ct], part);
        }
        part += __shfl_xor(part, 1, 64);
        part += __shfl_xor(part, 2, 64);
        part += __shfl_xor(part, 4, 64);
        part += __shfl_xor(part, 8, 64);
        if (l15 == 0) spart[w][rt*16 + l4*4 + r] = part;
      }
    }
  }
  __syncthreads();
  if (t < 64) {
    int p = rowbase + t;
    float raw = spart[0][t] + spart[1][t] + spart[2][t] + spart[3][t] + b3[0];
    scores[p] = (dist[p] <= CUTF) ? raw : 0.0f;
  }
}

// ---------------- kernel 6: softmax + weighted V + coord update ----------------
__global__ void k_combine(const float* __restrict__ scores, const int* __restrict__ idx,
    const float* __restrict__ vf, const float* __restrict__ gates,
    const float* __restrict__ cdiff, const float* __restrict__ ef,
    const float* __restrict__ ec, float* __restrict__ upd, float* __restrict__ outc) {
  int e = blockIdx.x, t = threadIdx.x;   // 128 threads
  __shared__ float wk[KNB], wg[KNB];
  __shared__ int jj[KNB];
  if (t < 64) {
    float sc = (t < KNB) ? scores[e*KNB + t] : -1e30f;
    float m = sc;
    #pragma unroll
    for (int mm = 1; mm < 32; mm <<= 1) m = fmaxf(m, __shfl_xor(m, mm, 64));
    m = fmaxf(m, 0.0f);
    float ex = (t < KNB) ? expf(sc - m) : 0.0f;
    float Z = ex;
    #pragma unroll
    for (int mm = 1; mm < 32; mm <<= 1) Z += __shfl_xor(Z, mm, 64);
    Z += 8160.0f * expf(-m);             // (E-K) zero-score tail
    if (t < KNB) {
      float w = ex / Z;
      int j = idx[e*KNB + t];
      jj[t] = j; wk[t] = w; wg[t] = w * gates[j];
    }
  }
  __syncthreads();
  float acc = 0.0f;
  #pragma unroll 4
  for (int kk = 0; kk < KNB; ++kk) acc = fmaf(wk[kk], vf[jj[kk]*HID + t], acc);
  upd[e*HID + t] = ef[e*HID + t] + acc;
  if (t < 3) {
    float csum = 0.0f;
    #pragma unroll 4
    for (int kk = 0; kk < KNB; ++kk) csum = fmaf(wg[kk], cdiff[(e*KNB + kk)*3 + t], csum);
    outc[e*3 + t] = ec[e*3 + t] + csum;
  }
}

// ---------------- kernel 7: output projection + residual + LayerNorm ----------------
__global__ void k_out(const float* __restrict__ upd, const float* __restrict__ ef,
    const float* __restrict__ Wo, const float* __restrict__ bo,
    const float* __restrict__ gamma, const float* __restrict__ beta,
    float* __restrict__ outf) {
  int e = blockIdx.x, o = threadIdx.x;   // 128 threads
  __shared__ float us[HID];
  __shared__ float red2[2];
  us[o] = upd[e*HID + o];
  __syncthreads();
  float a = 0.0f;
  #pragma unroll 8
  for (int d = 0; d < HID; ++d) a = fmaf(us[d], Wo[d*HID + o], a);
  float x = ef[e*HID + o] + a + bo[o];
  float s = x;
  #pragma unroll
  for (int m = 1; m < 64; m <<= 1) s += __shfl_xor(s, m, 64);
  if ((o & 63) == 0) red2[o >> 6] = s;
  __syncthreads();
  float mu = (red2[0] + red2[1]) * (1.0f/128.0f);
  __syncthreads();
  float dv = x - mu;
  float s2 = dv*dv;
  #pragma unroll
  for (int m = 1; m < 64; m <<= 1) s2 += __shfl_xor(s2, m, 64);
  if ((o & 63) == 0) red2[o >> 6] = s2;
  __syncthreads();
  float var = (red2[0] + red2[1]) * (1.0f/128.0f);
  outf[e*HID + o] = dv * rsqrtf(var + LNEPS) * gamma[o] + beta[o];
}

extern "C" void kernel_launch(void* const* d_in, const int* in_sizes, int n_in,
                              void* d_out, int out_size, void* d_ws, size_t ws_size,
                              hipStream_t stream) {
  const float* ef   = (const float*)d_in[0];
  const float* ec   = (const float*)d_in[1];
  const float* nc   = (const float*)d_in[2];
  const float* Wq   = (const float*)d_in[3];
  const float* Wk   = (const float*)d_in[4];
  const float* Wv   = (const float*)d_in[5];
  const float* W1   = (const float*)d_in[6];
  const float* b1   = (const float*)d_in[7];
  const float* W2   = (const float*)d_in[8];
  const float* b2   = (const float*)d_in[9];
  const float* W3   = (const float*)d_in[10];
  const float* b3   = (const float*)d_in[11];
  const float* Wg1  = (const float*)d_in[12];
  const float* bg1  = (const float*)d_in[13];
  const float* Wg2  = (const float*)d_in[14];
  const float* bg2  = (const float*)d_in[15];
  const float* Wo   = (const float*)d_in[16];
  const float* bo   = (const float*)d_in[17];
  const float* gamma= (const float*)d_in[18];
  const float* beta = (const float*)d_in[19];
  const float* centers = (const float*)d_in[20];
  const float* widths  = (const float*)d_in[21];
  const int*   eidx    = (const int*)d_in[22];

  float* outf = (float*)d_out;
  float* outc = outf + (size_t)E_N * HID;

  float4* cen4 = (float4*)d_ws;
  int*   idx   = (int*)(cen4 + E_N);
  float* dist  = (float*)(idx + E_N*KNB);
  float* cdiff = dist + E_N*KNB;
  float* dotv  = cdiff + 3*E_N*KNB;
  float* qf    = dotv + E_N*KNB;
  float* kf    = qf + (size_t)E_N*HID;
  float* vf    = kf + (size_t)E_N*HID;
  float* scores= vf + (size_t)E_N*HID;
  float* gates = scores + E_N*KNB;
  float* upd   = gates + E_N;
  u16*   Wt1   = (u16*)(upd + (size_t)E_N*HID);   // 128*320 bf16
  u16*   Wt2   = Wt1 + 128*320;                   // 128*128 bf16

  k_convw<<<128, 448, 0, stream>>>(W1, W2, Wt1, Wt2);
  k_prep<<<E_N/256, 256, 0, stream>>>(nc, eidx, cen4);
  k_topk<<<E_N, 256, 0, stream>>>(cen4, idx);
  k_qkv_gates<<<E_N, 128, 0, stream>>>(ef, Wq, Wk, Wv, Wg1, bg1, Wg2, bg2, qf, kf, vf, gates);
  k_geom<<<E_N*KNB/4, 256, 0, stream>>>(cen4, idx, qf, kf, dist, cdiff, dotv);
  k_mlp<<<E_N*KNB/64, 256, 0, stream>>>(qf, kf, idx, dist, dotv, Wt1, Wt2,
                                        W1, b1, b2, W3, b3, centers, widths, scores);
  k_combine<<<E_N, 128, 0, stream>>>(scores, idx, vf, gates, cdiff, ef, ec, upd, outc);
  k_out<<<E_N, 128, 0, stream>>>(upd, ef, Wo, bo, gamma, beta, outf);
}

// Round 4
// 285.676 us; speedup vs baseline: 3.5308x; 1.3272x over previous
//
#include <hip/hip_runtime.h>
#include <math.h>

#define E_N   8192
#define HID   128
#define NRAD  64
#define KNB   32
#define CUTF  10.0f
#define LNEPS 1e-5f

typedef unsigned short u16;
typedef unsigned int   u32;
typedef __bf16 bf16x8 __attribute__((ext_vector_type(8)));
typedef u16    u16x8  __attribute__((ext_vector_type(8)));
typedef float  f32x4  __attribute__((ext_vector_type(4)));

__device__ __forceinline__ u16 f2bf(float f) {
  unsigned u = __float_as_uint(f);
  unsigned r = (u + 0x7fffu + ((u >> 16) & 1u)) >> 16;   // RNE
  return (u16)r;
}

// ---------------- kernel 0a: bf16 weight prep (rbf block of W1, W2), transposed ----------------
__global__ void k_convw(const float* __restrict__ W1, const float* __restrict__ W2,
                        u16* __restrict__ Wt1r, u16* __restrict__ Wt2) {
  int b = blockIdx.x;            // output col 0..127
  int t = threadIdx.x;           // 0..191
  if (t < 64)       Wt1r[b*64 + t]        = f2bf(W1[(256+t)*HID + b]);   // rbf rows 256..319
  else if (t < 192) Wt2[b*HID + (t-64)]   = f2bf(W2[(t-64)*HID + b]);
}

// ---------------- kernel 0b: fused weight products Wqc = Wq@W1[0:128], Wkc = Wk@W1[128:256] ----------------
__global__ void k_fusew(const float* __restrict__ Wq, const float* __restrict__ Wk,
                        const float* __restrict__ W1,
                        float* __restrict__ Wqc, float* __restrict__ Wkc) {
  int r = blockIdx.x, o = threadIdx.x;   // 128 x 128
  float a = 0.f, b = 0.f;
  #pragma unroll 8
  for (int m = 0; m < 128; ++m) {
    a = fmaf(Wq[r*128+m], W1[m*128+o], a);
    b = fmaf(Wk[r*128+m], W1[(128+m)*128+o], b);
  }
  Wqc[r*128+o] = a; Wkc[r*128+o] = b;
}

// ---------------- kernel 1: edge centers + squared norms (packed float4) ----------------
__global__ void k_prep(const float* __restrict__ nc, const int* __restrict__ ei,
                       float4* __restrict__ cen4) {
  int e = blockIdx.x * 256 + threadIdx.x;
  if (e >= E_N) return;
  int a = ei[e], b = ei[E_N + e];
  float x = (nc[a*3+0] + nc[b*3+0]) * 0.5f;
  float y = (nc[a*3+1] + nc[b*3+1]) * 0.5f;
  float z = (nc[a*3+2] + nc[b*3+2]) * 0.5f;
  cen4[e] = make_float4(x, y, z, x*x + y*y + z*z);
}

// ---------------- kernel 2: top-K via 3-level radix select ----------------
__global__ __launch_bounds__(256) void k_topk(const float4* __restrict__ cen4,
                                              int* __restrict__ idxo) {
  const int row = blockIdx.x;
  const int t = threadIdx.x;
  const int lane = t & 63, w = t >> 6;
  __shared__ u32 hist[2048];
  __shared__ u32 red[4];
  __shared__ u32 bc_bin, bc_cless, bc_min, selc;

  const float4 me = cen4[row];
  u32 keys[32];
  #pragma unroll
  for (int s = 0; s < 32; ++s) {
    int j = t + (s << 8);
    float4 c = cen4[j];
    float dot = me.x*c.x + me.y*c.y + me.z*c.z;
    float d2 = (me.w + c.w) - 2.0f*dot;       // same expression as reference gram trick
    unsigned u = __float_as_uint(d2);
    keys[s] = (u & 0x80000000u) ? ~u : (u | 0x80000000u);
  }

  u32 want = 0, mask = 0;
  int need = KNB;
  u32 c_less = 0;

  #pragma unroll 1
  for (int lev = 0; lev < 3; ++lev) {
    const int sh = (lev == 0) ? 21 : (lev == 1) ? 10 : 0;
    const u32 bm = (lev == 2) ? 0x3FFu : 0x7FFu;

    for (int i = t; i < 2048; i += 256) hist[i] = 0;
    __syncthreads();
    #pragma unroll
    for (int s = 0; s < 32; ++s)
      if ((keys[s] & mask) == want)
        atomicAdd(&hist[(keys[s] >> sh) & bm], 1u);
    __syncthreads();

    u32 h8[8]; u32 p = 0;
    #pragma unroll
    for (int b = 0; b < 8; ++b) { h8[b] = hist[t*8 + b]; p += h8[b]; }
    int inc = (int)p;
    #pragma unroll
    for (int off = 1; off < 64; off <<= 1) {
      int v = __shfl_up(inc, off, 64);
      if (lane >= off) inc += v;
    }
    if (lane == 63) red[w] = (u32)inc;
    __syncthreads();
    u32 woff = 0;
    #pragma unroll
    for (int ww = 0; ww < 4; ++ww) woff += (ww < w) ? red[ww] : 0u;
    u32 cum = woff + (u32)inc - p;
    #pragma unroll
    for (int b = 0; b < 8; ++b) {
      if (cum < (u32)need && cum + h8[b] >= (u32)need) {
        bc_bin = (u32)(t*8 + b); bc_cless = cum;
      }
      cum += h8[b];
    }
    __syncthreads();
    u32 binId = bc_bin, cb = bc_cless;
    c_less += cb;
    need  -= (int)cb;
    want  |= binId << sh;
    mask  |= bm << sh;
    __syncthreads();
  }

  const u32 T = want;
  if (t == 0) selc = 0;
  __syncthreads();
  #pragma unroll
  for (int s = 0; s < 32; ++s) {
    if (keys[s] < T) {
      u32 pos = atomicAdd(&selc, 1u);
      idxo[row*KNB + pos] = t + (s << 8);
    }
  }
  for (int r = 0; r < need; ++r) {
    u32 lm = 0xFFFFFFFFu;
    #pragma unroll
    for (int s = 0; s < 32; ++s)
      if (keys[s] == T) { u32 j = (u32)(t + (s << 8)); lm = j < lm ? j : lm; }
    #pragma unroll
    for (int off = 1; off < 64; off <<= 1) {
      u32 o = (u32)__shfl_xor((int)lm, off, 64);
      lm = o < lm ? o : lm;
    }
    if (lane == 0) red[w] = lm;
    __syncthreads();
    if (t == 0) {
      u32 m0 = red[0] < red[1] ? red[0] : red[1];
      u32 m1 = red[2] < red[3] ? red[2] : red[3];
      u32 m = m0 < m1 ? m0 : m1;
      bc_min = m;
      idxo[row*KNB + (int)c_less + r] = (int)m;
    }
    __syncthreads();
    u32 jw = bc_min;
    if ((jw & 255u) == (u32)t) keys[jw >> 8] = 0xFFFFFFFFu;
  }
}

// ---------------- kernel 3: q,k,v + fused-projection rows + gates, 8 edges/block ----------------
__global__ __launch_bounds__(128) void k_qkv(const float* __restrict__ ef,
    const float* __restrict__ Wq, const float* __restrict__ Wk, const float* __restrict__ Wv,
    const float* __restrict__ Wqc, const float* __restrict__ Wkc, const float* __restrict__ b1,
    const float* __restrict__ Wg1, const float* __restrict__ bg1,
    const float* __restrict__ Wg2, const float* __restrict__ bg2,
    float* __restrict__ qf, float* __restrict__ kf, float* __restrict__ vf,
    float* __restrict__ qW1, float* __restrict__ kW1, float* __restrict__ gates) {
  const int o = threadIdx.x;
  const int e0 = blockIdx.x * 8;
  __shared__ float efs[8][128];
  __shared__ float vs[8][128];
  __shared__ float gred[8][2];

  #pragma unroll
  for (int e = 0; e < 8; ++e) efs[e][o] = ef[(e0+e)*HID + o];
  __syncthreads();

  float aq[8] = {0}, ak[8] = {0}, av[8] = {0}, aqc[8] = {0}, akc[8] = {0};
  #pragma unroll 4
  for (int d = 0; d < 128; ++d) {
    float wq = Wq[d*128+o], wk = Wk[d*128+o], wv = Wv[d*128+o];
    float wc1 = Wqc[d*128+o], wc2 = Wkc[d*128+o];
    #pragma unroll
    for (int e = 0; e < 8; ++e) {
      float a = efs[e][d];
      aq[e]  = fmaf(a, wq,  aq[e]);
      ak[e]  = fmaf(a, wk,  ak[e]);
      av[e]  = fmaf(a, wv,  av[e]);
      aqc[e] = fmaf(a, wc1, aqc[e]);
      akc[e] = fmaf(a, wc2, akc[e]);
    }
  }
  float bb1 = b1[o];
  #pragma unroll
  for (int e = 0; e < 8; ++e) {
    qf[(e0+e)*HID+o] = aq[e]; kf[(e0+e)*HID+o] = ak[e]; vf[(e0+e)*HID+o] = av[e];
    qW1[(e0+e)*HID+o] = aqc[e] + bb1;
    kW1[(e0+e)*HID+o] = akc[e];
    vs[e][o] = av[e];
  }
  __syncthreads();

  float ag[8] = {0};
  #pragma unroll 4
  for (int d = 0; d < 128; ++d) {
    float wg = Wg1[d*128+o];
    #pragma unroll
    for (int e = 0; e < 8; ++e) ag[e] = fmaf(vs[e][d], wg, ag[e]);
  }
  float bgo = bg1[o], w2 = Wg2[o];
  const int lane = o & 63, w = o >> 6;
  #pragma unroll
  for (int e = 0; e < 8; ++e) {
    float g = ag[e] + bgo;
    g = g / (1.0f + __expf(-g));
    float part = g * w2;
    #pragma unroll
    for (int m = 1; m < 64; m <<= 1) part += __shfl_xor(part, m, 64);
    if (lane == 0) gred[e][w] = part;
  }
  __syncthreads();
  if (o < 8) gates[e0+o] = 1.0f / (1.0f + __expf(-(gred[o][0] + gred[o][1] + bg2[0])));
}

// ---------------- kernel 4: per-pair geometry + q.k dot (4 lanes/pair) ----------------
__global__ void k_geom(const float4* __restrict__ cen4, const int* __restrict__ idx,
    const float* __restrict__ qf, const float* __restrict__ kf,
    float* __restrict__ dist, float* __restrict__ cdiff, float* __restrict__ dotv) {
  const int t = threadIdx.x;
  const int p = blockIdx.x * 64 + (t >> 2);
  const int sub = t & 3;
  const int e = p >> 5;
  const int j = idx[p];
  const float4* q4 = (const float4*)(qf + e*HID) + sub*8;
  const float4* k4 = (const float4*)(kf + j*HID) + sub*8;
  float s = 0.f;
  #pragma unroll
  for (int i = 0; i < 8; ++i) {
    float4 a = q4[i], b = k4[i];
    s += a.x*b.x + a.y*b.y + a.z*b.z + a.w*b.w;
  }
  s += __shfl_xor(s, 1, 64);
  s += __shfl_xor(s, 2, 64);
  if (sub == 0) {
    dotv[p] = s;
    float4 ce = cen4[e], cj = cen4[j];
    float dx = ce.x - cj.x, dy = ce.y - cj.y, dz = ce.z - cj.z;
    dist[p] = sqrtf(dx*dx + dy*dy + dz*dz);
    cdiff[p*3+0] = dx; cdiff[p*3+1] = dy; cdiff[p*3+2] = dz;
  }
}

// ---------------- kernel 5: fused attention MLP -> scores (bf16 MFMA, rbf-only GEMM1) ----------------
__global__ __launch_bounds__(256) void k_mlp(
    const int* __restrict__ idx, const float* __restrict__ dist,
    const float* __restrict__ dotv,
    const float* __restrict__ qW1, const float* __restrict__ kW1,
    const u16* __restrict__ Wt1r, const u16* __restrict__ Wt2,
    const float* __restrict__ W1,           // for w320 row
    const float* __restrict__ b2, const float* __restrict__ W3,
    const float* __restrict__ b3,
    const float* __restrict__ centers, const float* __restrict__ widths,
    float* __restrict__ scores) {
  __shared__ u16 sA[64*64];       // rbf tile, swizzled (8 KiB)
  __shared__ u16 sH[64*128];      // h tile, swizzled (16 KiB)
  __shared__ float spart[4][64];
  __shared__ float sQW[2][128];
  __shared__ float sDot[64];
  __shared__ int   sIdx[64];

  const int t  = threadIdx.x;
  const int w  = t >> 6, l = t & 63;
  const int l15 = l & 15, l4 = l >> 4;
  const int rowbase = blockIdx.x * 64;
  const int eBase = rowbase >> 5;           // two edges per block

  // ---- stage: rbf tile + per-row dot/idx + per-edge qW1 rows ----
  const int srow = t >> 2, sb = t & 3;
  const int sp = rowbase + srow;
  const float sdist = dist[sp];
  const float sincut = (sdist <= CUTF) ? 1.0f : 0.0f;
  {
    u16 tmp[16];
    #pragma unroll
    for (int i4 = 0; i4 < 4; ++i4) {
      float4 cc = *(const float4*)(centers + sb*16 + i4*4);
      float4 ww = *(const float4*)(widths  + sb*16 + i4*4);
      float c4[4] = {cc.x,cc.y,cc.z,cc.w}, w4[4] = {ww.x,ww.y,ww.z,ww.w};
      #pragma unroll
      for (int jj = 0; jj < 4; ++jj) {
        float df = sdist - c4[jj];
        tmp[i4*4+jj] = f2bf(__expf(-w4[jj]*df*df) * sincut);
      }
    }
    #pragma unroll
    for (int g = 0; g < 2; ++g) {
      u16x8 vv;
      #pragma unroll
      for (int jj = 0; jj < 8; ++jj) vv[jj] = tmp[g*8+jj];
      int widx = (srow*64 + sb*16 + g*8) ^ ((srow & 7) << 3);
      *(u16x8*)(&sA[widx]) = vv;
    }
  }
  sQW[t >> 7][t & 127] = qW1[(eBase + (t >> 7))*HID + (t & 127)];
  if (t < 64) { sDot[t] = dotv[rowbase + t]; sIdx[t] = idx[rowbase + t]; }
  __syncthreads();

  f32x4 acc[4][2];
  #pragma unroll
  for (int rt = 0; rt < 4; ++rt)
    #pragma unroll
    for (int ct = 0; ct < 2; ++ct) acc[rt][ct] = (f32x4){0.f,0.f,0.f,0.f};

  // ---- GEMM1: rbf (K=64) ----
  #pragma unroll
  for (int ks = 0; ks < 2; ++ks) {
    bf16x8 af[4], bfr[2];
    #pragma unroll
    for (int rt = 0; rt < 4; ++rt) {
      int row = rt*16 + l15;
      int aidx = (row*64 + ks*32 + l4*8) ^ ((row & 7) << 3);
      af[rt] = *(const bf16x8*)(&sA[aidx]);
    }
    #pragma unroll
    for (int ct = 0; ct < 2; ++ct) {
      int col = w*32 + ct*16 + l15;
      bfr[ct] = *(const bf16x8*)(&Wt1r[col*64 + ks*32 + l4*8]);
    }
    #pragma unroll
    for (int rt = 0; rt < 4; ++rt)
      #pragma unroll
      for (int ct = 0; ct < 2; ++ct)
        acc[rt][ct] = __builtin_amdgcn_mfma_f32_16x16x32_bf16(af[rt], bfr[ct], acc[rt][ct], 0, 0, 0);
  }

  // ---- epilogue 1: + qW1[e] + kW1[j] + dot*w320, silu -> sH bf16 (swizzled) ----
  {
    float w320[2], b2dummy;
    (void)b2dummy;
    #pragma unroll
    for (int ct = 0; ct < 2; ++ct) {
      int col = w*32 + ct*16 + l15;
      w320[ct] = W1[320*HID + col];
    }
    #pragma unroll
    for (int rt = 0; rt < 4; ++rt) {
      #pragma unroll
      for (int r = 0; r < 4; ++r) {
        int row = rt*16 + l4*4 + r;
        float dv = sDot[row];
        int jrow = sIdx[row];
        int eh = row >> 5;
        #pragma unroll
        for (int ct = 0; ct < 2; ++ct) {
          int col = w*32 + ct*16 + l15;
          float x = acc[rt][ct][r] + sQW[eh][col] + kW1[jrow*HID + col] + dv*w320[ct];
          float h = x / (1.0f + __expf(-x));
          sH[(row*128 + col) ^ ((row & 7) << 3)] = f2bf(h);
        }
      }
    }
  }
  __syncthreads();

  #pragma unroll
  for (int rt = 0; rt < 4; ++rt)
    #pragma unroll
    for (int ct = 0; ct < 2; ++ct) acc[rt][ct] = (f32x4){0.f,0.f,0.f,0.f};

  // ---- GEMM2: h @ W2 ----
  #pragma unroll
  for (int ks = 0; ks < 4; ++ks) {
    bf16x8 af[4], bfr[2];
    #pragma unroll
    for (int rt = 0; rt < 4; ++rt) {
      int row = rt*16 + l15;
      int aidx = (row*128 + ks*32 + l4*8) ^ ((row & 7) << 3);
      af[rt] = *(const bf16x8*)(&sH[aidx]);
    }
    #pragma unroll
    for (int ct = 0; ct < 2; ++ct) {
      int col = w*32 + ct*16 + l15;
      bfr[ct] = *(const bf16x8*)(&Wt2[col*128 + ks*32 + l4*8]);
    }
    #pragma unroll
    for (int rt = 0; rt < 4; ++rt)
      #pragma unroll
      for (int ct = 0; ct < 2; ++ct)
        acc[rt][ct] = __builtin_amdgcn_mfma_f32_16x16x32_bf16(af[rt], bfr[ct], acc[rt][ct], 0, 0, 0);
  }

  // ---- epilogue 2: silu, dot W3, reduce ----
  {
    float b2r[2], w3r[2];
    #pragma unroll
    for (int ct = 0; ct < 2; ++ct) {
      int col = w*32 + ct*16 + l15;
      b2r[ct] = b2[col]; w3r[ct] = W3[col];
    }
    #pragma unroll
    for (int rt = 0; rt < 4; ++rt) {
      #pragma unroll
      for (int r = 0; r < 4; ++r) {
        float part = 0.f;
        #pragma unroll
        for (int ct = 0; ct < 2; ++ct) {
          float x = acc[rt][ct][r] + b2r[ct];
          float h = x / (1.0f + __expf(-x));
          part = fmaf(h, w3r[ct], part);
        }
        part += __shfl_xor(part, 1, 64);
        part += __shfl_xor(part, 2, 64);
        part += __shfl_xor(part, 4, 64);
        part += __shfl_xor(part, 8, 64);
        if (l15 == 0) spart[w][rt*16 + l4*4 + r] = part;
      }
    }
  }
  __syncthreads();
  if (t < 64) {
    int p = rowbase + t;
    float raw = spart[0][t] + spart[1][t] + spart[2][t] + spart[3][t] + b3[0];
    scores[p] = (dist[p] <= CUTF) ? raw : 0.0f;
  }
}

// ---------------- kernel 6: softmax + weighted V + coord update ----------------
__global__ void k_combine(const float* __restrict__ scores, const int* __restrict__ idx,
    const float* __restrict__ vf, const float* __restrict__ gates,
    const float* __restrict__ cdiff, const float* __restrict__ ef,
    const float* __restrict__ ec, float* __restrict__ upd, float* __restrict__ outc) {
  int e = blockIdx.x, t = threadIdx.x;   // 128 threads
  __shared__ float wk[KNB], wg[KNB];
  __shared__ int jj[KNB];
  if (t < 64) {
    float sc = (t < KNB) ? scores[e*KNB + t] : -1e30f;
    float m = sc;
    #pragma unroll
    for (int mm = 1; mm < 32; mm <<= 1) m = fmaxf(m, __shfl_xor(m, mm, 64));
    m = fmaxf(m, 0.0f);
    float ex = (t < KNB) ? __expf(sc - m) : 0.0f;
    float Z = ex;
    #pragma unroll
    for (int mm = 1; mm < 32; mm <<= 1) Z += __shfl_xor(Z, mm, 64);
    Z += 8160.0f * __expf(-m);             // (E-K) zero-score tail
    if (t < KNB) {
      float w = ex / Z;
      int j = idx[e*KNB + t];
      jj[t] = j; wk[t] = w; wg[t] = w * gates[j];
    }
  }
  __syncthreads();
  float acc = 0.0f;
  #pragma unroll 4
  for (int kk = 0; kk < KNB; ++kk) acc = fmaf(wk[kk], vf[jj[kk]*HID + t], acc);
  upd[e*HID + t] = ef[e*HID + t] + acc;
  if (t < 3) {
    float csum = 0.0f;
    #pragma unroll 4
    for (int kk = 0; kk < KNB; ++kk) csum = fmaf(wg[kk], cdiff[(e*KNB + kk)*3 + t], csum);
    outc[e*3 + t] = ec[e*3 + t] + csum;
  }
}

// ---------------- kernel 7: output projection + residual + LayerNorm, 8 edges/block ----------------
__global__ __launch_bounds__(256) void k_out(const float* __restrict__ upd,
    const float* __restrict__ ef,
    const float* __restrict__ Wo, const float* __restrict__ bo,
    const float* __restrict__ gamma, const float* __restrict__ beta,
    float* __restrict__ outf) {
  const int t = threadIdx.x;
  const int e0 = blockIdx.x * 8;
  const int o = t & 127, h = t >> 7;
  __shared__ float us[8][128];
  __shared__ float xs[8][128];
  #pragma unroll
  for (int i = 0; i < 4; ++i) {
    int ii = t + i*256;
    us[ii >> 7][ii & 127] = upd[e0*HID + ii];
  }
  __syncthreads();
  float acc[4] = {0,0,0,0};
  #pragma unroll 4
  for (int d = 0; d < 128; ++d) {
    float wo = Wo[d*128+o];
    #pragma unroll
    for (int i = 0; i < 4; ++i) acc[i] = fmaf(us[h*4+i][d], wo, acc[i]);
  }
  float bb = bo[o];
  #pragma unroll
  for (int i = 0; i < 4; ++i) {
    int e = h*4+i;
    xs[e][o] = ef[(e0+e)*HID + o] + acc[i] + bb;
  }
  __syncthreads();
  const int w = t >> 6, lane = t & 63;
  #pragma unroll
  for (int ii = 0; ii < 2; ++ii) {
    int e = w*2 + ii;
    float a = xs[e][lane], b = xs[e][64+lane];
    float s1 = a + b, s2 = a*a + b*b;
    #pragma unroll
    for (int m = 1; m < 64; m <<= 1) {
      s1 += __shfl_xor(s1, m, 64);
      s2 += __shfl_xor(s2, m, 64);
    }
    float mu = s1 * (1.0f/128.0f);
    float var = s2 * (1.0f/128.0f) - mu*mu;
    float rs = rsqrtf(var + LNEPS);
    outf[(e0+e)*HID + lane]      = (a - mu)*rs*gamma[lane]      + beta[lane];
    outf[(e0+e)*HID + 64 + lane] = (b - mu)*rs*gamma[64+lane]   + beta[64+lane];
  }
}

extern "C" void kernel_launch(void* const* d_in, const int* in_sizes, int n_in,
                              void* d_out, int out_size, void* d_ws, size_t ws_size,
                              hipStream_t stream) {
  const float* ef   = (const float*)d_in[0];
  const float* ec   = (const float*)d_in[1];
  const float* nc   = (const float*)d_in[2];
  const float* Wq   = (const float*)d_in[3];
  const float* Wk   = (const float*)d_in[4];
  const float* Wv   = (const float*)d_in[5];
  const float* W1   = (const float*)d_in[6];
  const float* b1   = (const float*)d_in[7];
  const float* W2   = (const float*)d_in[8];
  const float* b2   = (const float*)d_in[9];
  const float* W3   = (const float*)d_in[10];
  const float* b3   = (const float*)d_in[11];
  const float* Wg1  = (const float*)d_in[12];
  const float* bg1  = (const float*)d_in[13];
  const float* Wg2  = (const float*)d_in[14];
  const float* bg2  = (const float*)d_in[15];
  const float* Wo   = (const float*)d_in[16];
  const float* bo   = (const float*)d_in[17];
  const float* gamma= (const float*)d_in[18];
  const float* beta = (const float*)d_in[19];
  const float* centers = (const float*)d_in[20];
  const float* widths  = (const float*)d_in[21];
  const int*   eidx    = (const int*)d_in[22];

  float* outf = (float*)d_out;
  float* outc = outf + (size_t)E_N * HID;

  // workspace layout (16B-aligned chunks first)
  float4* cen4 = (float4*)d_ws;                        // 8192 * 16B
  u16*   Wt1r  = (u16*)(cen4 + E_N);                   // 128*64 bf16
  u16*   Wt2   = Wt1r + 128*64;                        // 128*128 bf16
  int*   idx   = (int*)(Wt2 + 128*128);
  float* dist  = (float*)(idx + E_N*KNB);
  float* cdiff = dist + E_N*KNB;
  float* dotv  = cdiff + 3*E_N*KNB;
  float* qf    = dotv + E_N*KNB;
  float* kf    = qf + (size_t)E_N*HID;
  float* vf    = kf + (size_t)E_N*HID;
  float* qW1   = vf + (size_t)E_N*HID;
  float* kW1   = qW1 + (size_t)E_N*HID;
  float* scores= kW1 + (size_t)E_N*HID;
  float* gates = scores + E_N*KNB;
  float* upd   = gates + E_N;
  float* Wqc   = upd + (size_t)E_N*HID;                // 128*128 f32
  float* Wkc   = Wqc + 128*128;                        // 128*128 f32

  k_convw<<<128, 192, 0, stream>>>(W1, W2, Wt1r, Wt2);
  k_fusew<<<128, 128, 0, stream>>>(Wq, Wk, W1, Wqc, Wkc);
  k_prep<<<E_N/256, 256, 0, stream>>>(nc, eidx, cen4);
  k_topk<<<E_N, 256, 0, stream>>>(cen4, idx);
  k_qkv<<<E_N/8, 128, 0, stream>>>(ef, Wq, Wk, Wv, Wqc, Wkc, b1, Wg1, bg1, Wg2, bg2,
                                   qf, kf, vf, qW1, kW1, gates);
  k_geom<<<E_N*KNB/64, 256, 0, stream>>>(cen4, idx, qf, kf, dist, cdiff, dotv);
  k_mlp<<<E_N*KNB/64, 256, 0, stream>>>(idx, dist, dotv, qW1, kW1, Wt1r, Wt2,
                                        W1, b2, W3, b3, centers, widths, scores);
  k_combine<<<E_N, 128, 0, stream>>>(scores, idx, vf, gates, cdiff, ef, ec, upd, outc);
  k_out<<<E_N/8, 256, 0, stream>>>(upd, ef, Wo, bo, gamma, beta, outf);
}